// Round 2
// baseline (445.345 us; speedup 1.0000x reference)
//
#include <hip/hip_runtime.h>
#include <hip/hip_bf16.h>
#include <math.h>

// Problem constants
constexpr int kD  = 1024;
constexpr int kH1 = 4096;
constexpr int kO  = 1024;
constexpr int kE  = 8;
constexpr int kB  = 8192;

// GEMM tiling
constexpr int BM = 128;
constexpr int BN = 128;
constexpr int BK = 32;
constexpr int MAXT = kB / BM + kE;  // 72 row-tiles upper bound

typedef __attribute__((ext_vector_type(8))) short short8;
typedef __attribute__((ext_vector_type(4))) float f32x4;

__device__ __forceinline__ unsigned short f2bf(float f) {
  // round-to-nearest-even fp32 -> bf16 (inputs are finite)
  unsigned int u = __float_as_uint(f);
  u += 0x7fffu + ((u >> 16) & 1u);
  return (unsigned short)(u >> 16);
}

__device__ __forceinline__ float gelu_exact(float v) {
  return 0.5f * v * (1.0f + erff(v * 0.70710678118654752f));
}

// ---------------------------------------------------------------------------
// Setup: counts per expert, permutation (grouped by expert), tile table.
// tiles[t] = {expert, row_start (perm space), nrows, 0}
// ---------------------------------------------------------------------------
__global__ __launch_bounds__(256) void setup_kernel(const int* __restrict__ eid,
                                                    int* __restrict__ perm,
                                                    int* __restrict__ tiles) {
  __shared__ int cnt[kE];
  __shared__ int off[kE];
  __shared__ int cur[kE];
  int t = threadIdx.x;
  if (t < kE) { cnt[t] = 0; cur[t] = 0; }
  __syncthreads();
  for (int i = t; i < kB; i += 256) atomicAdd(&cnt[eid[i]], 1);
  __syncthreads();
  if (t == 0) {
    int o = 0, nt = 0;
    for (int e = 0; e < kE; ++e) {
      off[e] = o;
      int c = cnt[e];
      for (int r = 0; r < c; r += BM) {
        tiles[nt * 4 + 0] = e;
        tiles[nt * 4 + 1] = o + r;
        tiles[nt * 4 + 2] = (c - r < BM) ? (c - r) : BM;
        tiles[nt * 4 + 3] = 0;
        ++nt;
      }
      o += c;
    }
    for (; nt < MAXT; ++nt) {
      tiles[nt * 4 + 0] = 0; tiles[nt * 4 + 1] = 0;
      tiles[nt * 4 + 2] = 0; tiles[nt * 4 + 3] = 0;
    }
  }
  __syncthreads();
  for (int i = t; i < kB; i += 256) {
    int e = eid[i];
    int p = off[e] + atomicAdd(&cur[e], 1);
    perm[p] = i;
  }
}

// ---------------------------------------------------------------------------
// Gather x rows into perm order, fp32 -> bf16.  xg is [kB+BM][kD] bf16.
// ---------------------------------------------------------------------------
__global__ __launch_bounds__(256) void gather_kernel(const float* __restrict__ x,
                                                     const int* __restrict__ perm,
                                                     unsigned short* __restrict__ xg) {
  int idx = blockIdx.x * 256 + threadIdx.x;       // one thread = 8 elements
  int pos = idx >> 7;                              // kD/8 = 128 threads per row
  int c   = (idx & 127) << 3;
  int row = perm[pos];
  const float4* s = (const float4*)(x + (size_t)row * kD + c);
  float4 f0 = s[0], f1 = s[1];
  short8 v;
  v[0] = (short)f2bf(f0.x); v[1] = (short)f2bf(f0.y);
  v[2] = (short)f2bf(f0.z); v[3] = (short)f2bf(f0.w);
  v[4] = (short)f2bf(f1.x); v[5] = (short)f2bf(f1.y);
  v[6] = (short)f2bf(f1.z); v[7] = (short)f2bf(f1.w);
  *(short8*)(xg + (size_t)pos * kD + c) = v;
}

// ---------------------------------------------------------------------------
// Grouped GEMM:  C[m][n] = sum_k A[m][k] * W[e][n][k]   (both K-major, "BT")
// A: bf16 [rows][K] in perm space (contiguous per expert).
// W: fp32 [kE][N][K], converted to bf16 at staging time.
// OUTBF: write bf16 (gelu) to out_bf in perm space; else fp32 (+bias),
//        scattered to original rows via perm.
// ---------------------------------------------------------------------------
template <int K, int N, bool GELU, bool BIAS, bool OUTBF>
__global__ __launch_bounds__(256) void gemm_kernel(
    const unsigned short* __restrict__ Amat,
    const float* __restrict__ Wmat,
    const float* __restrict__ bias,
    const int* __restrict__ tiles,
    const int* __restrict__ perm,
    unsigned short* __restrict__ out_bf,
    float* __restrict__ out_f) {
  const int ti = blockIdx.x;
  const int e  = tiles[ti * 4 + 0];
  const int rs = tiles[ti * 4 + 1];
  const int nr = tiles[ti * 4 + 2];
  if (nr == 0) return;
  const int n0 = blockIdx.y * BN;

  __shared__ __align__(16) unsigned short As[2][BM * BK];
  __shared__ __align__(16) unsigned short Bs[2][BM * BK];

  const int t  = threadIdx.x;
  const int l  = t & 63;
  const int w  = t >> 6;
  const int wr = w >> 1;   // wave row (0..1), 64 rows each
  const int wc = w & 1;    // wave col (0..1), 64 cols each

  const float* Wp = Wmat + (size_t)e * N * K;

  f32x4 acc[4][4] = {};

  auto stage = [&](int buf, int k0) {
    // A tile: 128x32 bf16 = 8KB, linear global_load_lds, 2 issues x 4KB
#pragma unroll
    for (int i = 0; i < 2; ++i) {
      int elem = (i * 256 + t) * 8;         // bf16 element index in tile
      int r = elem >> 5;                    // /BK
      int c = elem & (BK - 1);
      const unsigned short* src = Amat + (size_t)(rs + r) * K + k0 + c;
      __builtin_amdgcn_global_load_lds(
          (const __attribute__((address_space(1))) unsigned int*)src,
          (__attribute__((address_space(3))) unsigned int*)(&As[buf][elem]),
          16, 0, 0);
    }
    // B tile: 128 rows (N dim) x 32 K fp32 -> bf16, reg-staged
#pragma unroll
    for (int i = 0; i < 2; ++i) {
      int elem = (i * 256 + t) * 8;
      int r = elem >> 5;
      int c = elem & (BK - 1);
      const float4* src = (const float4*)(Wp + (size_t)(n0 + r) * K + k0 + c);
      float4 f0 = src[0], f1 = src[1];
      short8 v;
      v[0] = (short)f2bf(f0.x); v[1] = (short)f2bf(f0.y);
      v[2] = (short)f2bf(f0.z); v[3] = (short)f2bf(f0.w);
      v[4] = (short)f2bf(f1.x); v[5] = (short)f2bf(f1.y);
      v[6] = (short)f2bf(f1.z); v[7] = (short)f2bf(f1.w);
      *(short8*)&Bs[buf][elem] = v;
    }
  };

  stage(0, 0);
  __syncthreads();

  constexpr int NK = K / BK;
  for (int kt = 0; kt < NK; ++kt) {
    int cur = kt & 1;
    if (kt + 1 < NK) stage(cur ^ 1, (kt + 1) * BK);

    short8 a[4], b[4];
#pragma unroll
    for (int m = 0; m < 4; ++m)
      a[m] = *(const short8*)&As[cur][(wr * 64 + m * 16 + (l & 15)) * BK + (l >> 4) * 8];
#pragma unroll
    for (int n = 0; n < 4; ++n)
      b[n] = *(const short8*)&Bs[cur][(wc * 64 + n * 16 + (l & 15)) * BK + (l >> 4) * 8];

#pragma unroll
    for (int m = 0; m < 4; ++m)
#pragma unroll
      for (int n = 0; n < 4; ++n)
        acc[m][n] = __builtin_amdgcn_mfma_f32_16x16x32_bf16(a[m], b[n], acc[m][n], 0, 0, 0);

    __syncthreads();
  }

  // Epilogue.  C/D frag: col = lane&15, row = (lane>>4)*4 + reg   [m89]
  const int lr4 = (l >> 4) * 4;
  const int lc  = l & 15;
#pragma unroll
  for (int m = 0; m < 4; ++m) {
#pragma unroll
    for (int r = 0; r < 4; ++r) {
      int row_t = wr * 64 + m * 16 + lr4 + r;
      if (row_t < nr) {
        if constexpr (OUTBF) {
          unsigned short* dst = out_bf + (size_t)(rs + row_t) * N + n0;
#pragma unroll
          for (int n = 0; n < 4; ++n) {
            float v = acc[m][n][r];
            if constexpr (GELU) v = gelu_exact(v);
            dst[wc * 64 + n * 16 + lc] = f2bf(v);
          }
        } else {
          int orig = perm[rs + row_t];
          float* dst = out_f + (size_t)orig * N + n0;
#pragma unroll
          for (int n = 0; n < 4; ++n) {
            float v = acc[m][n][r];
            if constexpr (BIAS) v += bias[(size_t)e * N + n0 + wc * 64 + n * 16 + lc];
            dst[wc * 64 + n * 16 + lc] = v;
          }
        }
      }
    }
  }
}

// ---------------------------------------------------------------------------
extern "C" void kernel_launch(void* const* d_in, const int* in_sizes, int n_in,
                              void* d_out, int out_size, void* d_ws, size_t ws_size,
                              hipStream_t stream) {
  const float* x  = (const float*)d_in[0];
  const int*  eid = (const int*)d_in[1];
  const float* W1 = (const float*)d_in[2];
  const float* W2 = (const float*)d_in[3];
  const float* b2 = (const float*)d_in[4];
  float* y = (float*)d_out;

  char* ws = (char*)d_ws;
  int* perm  = (int*)ws;                                   // kB ints
  int* tiles = (int*)(ws + 32768);                         // MAXT*4 ints
  unsigned short* xg = (unsigned short*)(ws + 36864);      // [kB+BM][kD] bf16
  size_t xg_bytes = (size_t)(kB + BM) * kD * 2;
  unsigned short* h  = (unsigned short*)(ws + 36864 + xg_bytes);  // [kB+BM][kH1] bf16

  setup_kernel<<<1, 256, 0, stream>>>(eid, perm, tiles);
  gather_kernel<<<(kB * kD / 8) / 256, 256, 0, stream>>>(x, perm, xg);

  // GEMM1: h = gelu(xg @ W1[e]^T), bf16 out, perm space
  gemm_kernel<kD, kH1, true, false, true>
      <<<dim3(MAXT, kH1 / BN), 256, 0, stream>>>(xg, W1, nullptr, tiles, perm, h, nullptr);

  // GEMM2: y[orig] = h @ W2[e]^T + b2[e], fp32 out, scattered
  gemm_kernel<kH1, kO, false, true, false>
      <<<dim3(MAXT, kO / BN), 256, 0, stream>>>(h, W2, b2, tiles, perm, nullptr, y);
}

// Round 3
// 374.961 us; speedup vs baseline: 1.1877x; 1.1877x over previous
//
#include <hip/hip_runtime.h>
#include <hip/hip_bf16.h>
#include <math.h>

// Problem constants
constexpr int kD  = 1024;
constexpr int kH1 = 4096;
constexpr int kO  = 1024;
constexpr int kE  = 8;
constexpr int kB  = 8192;

// GEMM tiling
constexpr int BM = 128;
constexpr int BN = 128;
constexpr int BK = 32;
constexpr int MAXT = kB / BM + kE;  // 72 row-tiles upper bound

typedef __attribute__((ext_vector_type(8))) short short8;
typedef __attribute__((ext_vector_type(4))) float f32x4;

__device__ __forceinline__ unsigned short f2bf(float f) {
  // round-to-nearest-even fp32 -> bf16 (inputs are finite)
  unsigned int u = __float_as_uint(f);
  u += 0x7fffu + ((u >> 16) & 1u);
  return (unsigned short)(u >> 16);
}

__device__ __forceinline__ float gelu_exact(float v) {
  return 0.5f * v * (1.0f + erff(v * 0.70710678118654752f));
}

// ---------------------------------------------------------------------------
// Setup: counts per expert, permutation (grouped by expert), tile table.
// tiles[t] = {expert, row_start (perm space), nrows, 0}
// ---------------------------------------------------------------------------
__global__ __launch_bounds__(256) void setup_kernel(const int* __restrict__ eid,
                                                    int* __restrict__ perm,
                                                    int* __restrict__ tiles) {
  __shared__ int cnt[kE];
  __shared__ int off[kE];
  __shared__ int cur[kE];
  int t = threadIdx.x;
  if (t < kE) { cnt[t] = 0; cur[t] = 0; }
  __syncthreads();
  for (int i = t; i < kB; i += 256) atomicAdd(&cnt[eid[i]], 1);
  __syncthreads();
  if (t == 0) {
    int o = 0, nt = 0;
    for (int e = 0; e < kE; ++e) {
      off[e] = o;
      int c = cnt[e];
      for (int r = 0; r < c; r += BM) {
        tiles[nt * 4 + 0] = e;
        tiles[nt * 4 + 1] = o + r;
        tiles[nt * 4 + 2] = (c - r < BM) ? (c - r) : BM;
        tiles[nt * 4 + 3] = 0;
        ++nt;
      }
      o += c;
    }
    for (; nt < MAXT; ++nt) {
      tiles[nt * 4 + 0] = 0; tiles[nt * 4 + 1] = 0;
      tiles[nt * 4 + 2] = 0; tiles[nt * 4 + 3] = 0;
    }
  }
  __syncthreads();
  for (int i = t; i < kB; i += 256) {
    int e = eid[i];
    int p = off[e] + atomicAdd(&cur[e], 1);
    perm[p] = i;
  }
}

// ---------------------------------------------------------------------------
// Gather x rows into perm order, fp32 -> bf16.  xg is [kB+BM][kD] bf16.
// ---------------------------------------------------------------------------
__global__ __launch_bounds__(256) void gather_kernel(const float* __restrict__ x,
                                                     const int* __restrict__ perm,
                                                     unsigned short* __restrict__ xg) {
  int idx = blockIdx.x * 256 + threadIdx.x;       // one thread = 8 elements
  int pos = idx >> 7;                              // kD/8 = 128 threads per row
  int c   = (idx & 127) << 3;
  int row = perm[pos];
  const float4* s = (const float4*)(x + (size_t)row * kD + c);
  float4 f0 = s[0], f1 = s[1];
  short8 v;
  v[0] = (short)f2bf(f0.x); v[1] = (short)f2bf(f0.y);
  v[2] = (short)f2bf(f0.z); v[3] = (short)f2bf(f0.w);
  v[4] = (short)f2bf(f1.x); v[5] = (short)f2bf(f1.y);
  v[6] = (short)f2bf(f1.z); v[7] = (short)f2bf(f1.w);
  *(short8*)(xg + (size_t)pos * kD + c) = v;
}

// ---------------------------------------------------------------------------
// Bulk fp32 -> bf16 convert (weights).  n8 = elements/8.
// ---------------------------------------------------------------------------
__global__ __launch_bounds__(256) void convert_kernel(const float* __restrict__ src,
                                                      unsigned short* __restrict__ dst,
                                                      int n8) {
  int stride = gridDim.x * 256;
  for (int i = blockIdx.x * 256 + threadIdx.x; i < n8; i += stride) {
    const float4* s = (const float4*)(src + (size_t)i * 8);
    float4 f0 = s[0], f1 = s[1];
    short8 v;
    v[0] = (short)f2bf(f0.x); v[1] = (short)f2bf(f0.y);
    v[2] = (short)f2bf(f0.z); v[3] = (short)f2bf(f0.w);
    v[4] = (short)f2bf(f1.x); v[5] = (short)f2bf(f1.y);
    v[6] = (short)f2bf(f1.z); v[7] = (short)f2bf(f1.w);
    *(short8*)(dst + (size_t)i * 8) = v;
  }
}

// ---------------------------------------------------------------------------
// Grouped GEMM:  C[m][n] = sum_k A[m][k] * B[e][n][k]   (both K-major, "BT")
// A: bf16 [rows][K] in perm space (contiguous per expert).
// B: bf16 [N][K] for the CURRENT pass's weights (pre-converted), per expert.
// Both operands staged via global_load_lds width=16 (m97 structure).
// OUTBF: write bf16 (gelu) to out_bf in perm space; else fp32 (+bias),
//        scattered to original rows via perm.
// ---------------------------------------------------------------------------
template <int K, int N, bool GELU, bool BIAS, bool OUTBF>
__global__ __launch_bounds__(256) void gemm_kernel(
    const unsigned short* __restrict__ Amat,
    const unsigned short* __restrict__ Bmat,
    const float* __restrict__ bias,
    const int* __restrict__ tiles,
    const int* __restrict__ perm,
    unsigned short* __restrict__ out_bf,
    float* __restrict__ out_f) {
  const int ti = blockIdx.x;
  const int e  = tiles[ti * 4 + 0];
  const int rs = tiles[ti * 4 + 1];
  const int nr = tiles[ti * 4 + 2];
  if (nr == 0) return;
  const int n0 = blockIdx.y * BN;

  __shared__ __align__(16) unsigned short As[2][BM * BK];
  __shared__ __align__(16) unsigned short Bs[2][BM * BK];

  const int t  = threadIdx.x;
  const int l  = t & 63;
  const int w  = t >> 6;
  const int wr = w >> 1;   // wave row (0..1), 64 rows each
  const int wc = w & 1;    // wave col (0..1), 64 cols each

  const unsigned short* Bp = Bmat + (size_t)e * N * K;

  f32x4 acc[4][4] = {};

  auto stage = [&](int buf, int k0) {
    // A tile: 128x32 bf16 = 8KB, linear global_load_lds, 2 issues x 4KB
#pragma unroll
    for (int i = 0; i < 2; ++i) {
      int elem = (i * 256 + t) * 8;         // bf16 element index in tile
      int r = elem >> 5;                    // /BK
      int c = elem & (BK - 1);
      const unsigned short* src = Amat + (size_t)(rs + r) * K + k0 + c;
      __builtin_amdgcn_global_load_lds(
          (const __attribute__((address_space(1))) unsigned int*)src,
          (__attribute__((address_space(3))) unsigned int*)(&As[buf][elem]),
          16, 0, 0);
    }
    // B tile: 128(N) x 32(K) bf16 = 8KB, same linear global_load_lds
#pragma unroll
    for (int i = 0; i < 2; ++i) {
      int elem = (i * 256 + t) * 8;
      int r = elem >> 5;
      int c = elem & (BK - 1);
      const unsigned short* src = Bp + (size_t)(n0 + r) * K + k0 + c;
      __builtin_amdgcn_global_load_lds(
          (const __attribute__((address_space(1))) unsigned int*)src,
          (__attribute__((address_space(3))) unsigned int*)(&Bs[buf][elem]),
          16, 0, 0);
    }
  };

  stage(0, 0);
  __syncthreads();

  constexpr int NK = K / BK;
  for (int kt = 0; kt < NK; ++kt) {
    int cur = kt & 1;
    if (kt + 1 < NK) stage(cur ^ 1, (kt + 1) * BK);

    short8 a[4], b[4];
#pragma unroll
    for (int m = 0; m < 4; ++m)
      a[m] = *(const short8*)&As[cur][(wr * 64 + m * 16 + (l & 15)) * BK + (l >> 4) * 8];
#pragma unroll
    for (int n = 0; n < 4; ++n)
      b[n] = *(const short8*)&Bs[cur][(wc * 64 + n * 16 + (l & 15)) * BK + (l >> 4) * 8];

#pragma unroll
    for (int m = 0; m < 4; ++m)
#pragma unroll
      for (int n = 0; n < 4; ++n)
        acc[m][n] = __builtin_amdgcn_mfma_f32_16x16x32_bf16(a[m], b[n], acc[m][n], 0, 0, 0);

    __syncthreads();
  }

  // Epilogue.  C/D frag: col = lane&15, row = (lane>>4)*4 + reg   [m89]
  const int lr4 = (l >> 4) * 4;
  const int lc  = l & 15;
#pragma unroll
  for (int m = 0; m < 4; ++m) {
#pragma unroll
    for (int r = 0; r < 4; ++r) {
      int row_t = wr * 64 + m * 16 + lr4 + r;
      if (row_t < nr) {
        if constexpr (OUTBF) {
          unsigned short* dst = out_bf + (size_t)(rs + row_t) * N + n0;
#pragma unroll
          for (int n = 0; n < 4; ++n) {
            float v = acc[m][n][r];
            if constexpr (GELU) v = gelu_exact(v);
            dst[wc * 64 + n * 16 + lc] = f2bf(v);
          }
        } else {
          int orig = perm[rs + row_t];
          float* dst = out_f + (size_t)orig * N + n0;
#pragma unroll
          for (int n = 0; n < 4; ++n) {
            float v = acc[m][n][r];
            if constexpr (BIAS) v += bias[(size_t)e * N + n0 + wc * 64 + n * 16 + lc];
            dst[wc * 64 + n * 16 + lc] = v;
          }
        }
      }
    }
  }
}

// ---------------------------------------------------------------------------
extern "C" void kernel_launch(void* const* d_in, const int* in_sizes, int n_in,
                              void* d_out, int out_size, void* d_ws, size_t ws_size,
                              hipStream_t stream) {
  const float* x  = (const float*)d_in[0];
  const int*  eid = (const int*)d_in[1];
  const float* W1 = (const float*)d_in[2];
  const float* W2 = (const float*)d_in[3];
  const float* b2 = (const float*)d_in[4];
  float* y = (float*)d_out;

  char* ws = (char*)d_ws;
  int* perm  = (int*)ws;                                   // kB ints (32KB)
  int* tiles = (int*)(ws + 32768);                         // MAXT*4 ints
  unsigned short* xg = (unsigned short*)(ws + 36864);      // [kB+BM][kD] bf16
  size_t xg_bytes = (size_t)(kB + BM) * kD * 2;            // 17,039,360
  unsigned short* h  = (unsigned short*)(ws + 36864 + xg_bytes);  // [kB+BM][kH1] bf16
  size_t h_bytes = (size_t)(kB + BM) * kH1 * 2;            // 68,157,440
  // Shared weight buffer: holds bf16(W1) during GEMM1, then bf16(W2) during
  // GEMM2 (both are E*4096*1024 elements = 67,108,864 B).
  unsigned short* Wb = (unsigned short*)(ws + 36864 + xg_bytes + h_bytes);

  constexpr int kWelems8 = kE * kH1 * kD / 8;  // 4,194,304 vec8 per weight

  setup_kernel<<<1, 256, 0, stream>>>(eid, perm, tiles);
  gather_kernel<<<(kB * kD / 8) / 256, 256, 0, stream>>>(x, perm, xg);

  // W1 -> bf16
  convert_kernel<<<2048, 256, 0, stream>>>(W1, Wb, kWelems8);

  // GEMM1: h = gelu(xg @ W1[e]^T), bf16 out, perm space
  gemm_kernel<kD, kH1, true, false, true>
      <<<dim3(MAXT, kH1 / BN), 256, 0, stream>>>(xg, Wb, nullptr, tiles, perm, h, nullptr);

  // W2 -> bf16 (reuses Wb; stream order serializes after GEMM1)
  convert_kernel<<<2048, 256, 0, stream>>>(W2, Wb, kWelems8);

  // GEMM2: y[orig] = h @ W2[e]^T + b2[e], fp32 out, scattered
  gemm_kernel<kH1, kO, false, true, false>
      <<<dim3(MAXT, kO / BN), 256, 0, stream>>>(h, Wb, b2, tiles, perm, nullptr, y);
}

// Round 4
// 333.221 us; speedup vs baseline: 1.3365x; 1.1253x over previous
//
#include <hip/hip_runtime.h>
#include <hip/hip_bf16.h>
#include <math.h>

// Problem constants
constexpr int kD  = 1024;
constexpr int kH1 = 4096;
constexpr int kO  = 1024;
constexpr int kE  = 8;
constexpr int kB  = 8192;

constexpr int BM = 256;            // row-tile
constexpr int MAXT = kB / BM + kE; // 40 row-tiles upper bound

typedef __attribute__((ext_vector_type(8))) short short8;
typedef __attribute__((ext_vector_type(4))) float f32x4;

__device__ __forceinline__ unsigned short f2bf(float f) {
  unsigned int u = __float_as_uint(f);
  u += 0x7fffu + ((u >> 16) & 1u);
  return (unsigned short)(u >> 16);
}

__device__ __forceinline__ float gelu_exact(float v) {
  return 0.5f * v * (1.0f + erff(v * 0.70710678118654752f));
}

// ---------------------------------------------------------------------------
// Setup: counts per expert, permutation (grouped by expert), 256-row tiles.
// ---------------------------------------------------------------------------
__global__ __launch_bounds__(256) void setup_kernel(const int* __restrict__ eid,
                                                    int* __restrict__ perm,
                                                    int* __restrict__ tiles) {
  __shared__ int cnt[kE];
  __shared__ int off[kE];
  __shared__ int cur[kE];
  int t = threadIdx.x;
  if (t < kE) { cnt[t] = 0; cur[t] = 0; }
  __syncthreads();
  for (int i = t; i < kB; i += 256) atomicAdd(&cnt[eid[i]], 1);
  __syncthreads();
  if (t == 0) {
    int o = 0, nt = 0;
    for (int e = 0; e < kE; ++e) {
      off[e] = o;
      int c = cnt[e];
      for (int r = 0; r < c; r += BM) {
        tiles[nt * 4 + 0] = e;
        tiles[nt * 4 + 1] = o + r;
        tiles[nt * 4 + 2] = (c - r < BM) ? (c - r) : BM;
        tiles[nt * 4 + 3] = 0;
        ++nt;
      }
      o += c;
    }
    for (; nt < MAXT; ++nt) {
      tiles[nt * 4 + 0] = 0; tiles[nt * 4 + 1] = 0;
      tiles[nt * 4 + 2] = 0; tiles[nt * 4 + 3] = 0;
    }
  }
  __syncthreads();
  for (int i = t; i < kB; i += 256) {
    int e = eid[i];
    int p = off[e] + atomicAdd(&cur[e], 1);
    perm[p] = i;
  }
}

// ---------------------------------------------------------------------------
// Gather x rows into perm order, fp32 -> bf16.  xg is [kB+BM][kD] bf16.
// ---------------------------------------------------------------------------
__global__ __launch_bounds__(256) void gather_kernel(const float* __restrict__ x,
                                                     const int* __restrict__ perm,
                                                     unsigned short* __restrict__ xg) {
  int idx = blockIdx.x * 256 + threadIdx.x;
  int pos = idx >> 7;
  int c   = (idx & 127) << 3;
  int row = perm[pos];
  const float4* s = (const float4*)(x + (size_t)row * kD + c);
  float4 f0 = s[0], f1 = s[1];
  short8 v;
  v[0] = (short)f2bf(f0.x); v[1] = (short)f2bf(f0.y);
  v[2] = (short)f2bf(f0.z); v[3] = (short)f2bf(f0.w);
  v[4] = (short)f2bf(f1.x); v[5] = (short)f2bf(f1.y);
  v[6] = (short)f2bf(f1.z); v[7] = (short)f2bf(f1.w);
  *(short8*)(xg + (size_t)pos * kD + c) = v;
}

// ---------------------------------------------------------------------------
// Bulk fp32 -> bf16 convert (weights).
// ---------------------------------------------------------------------------
__global__ __launch_bounds__(256) void convert_kernel(const float* __restrict__ src,
                                                      unsigned short* __restrict__ dst,
                                                      int n8) {
  int stride = gridDim.x * 256;
  for (int i = blockIdx.x * 256 + threadIdx.x; i < n8; i += stride) {
    const float4* s = (const float4*)(src + (size_t)i * 8);
    float4 f0 = s[0], f1 = s[1];
    short8 v;
    v[0] = (short)f2bf(f0.x); v[1] = (short)f2bf(f0.y);
    v[2] = (short)f2bf(f0.z); v[3] = (short)f2bf(f0.w);
    v[4] = (short)f2bf(f1.x); v[5] = (short)f2bf(f1.y);
    v[6] = (short)f2bf(f1.z); v[7] = (short)f2bf(f1.w);
    *(short8*)(dst + (size_t)i * 8) = v;
  }
}

// ---------------------------------------------------------------------------
// 256x256 8-phase grouped GEMM (m201-style).  C = A(bf16, K-major) x B^T.
// 512 threads = 8 waves (wave w: r0=(w>>2)*64, c0=(w&3)*32; covers rows
// {r0,r0+128} x cols {c0,c0+128}).  BK=64; 2 LDS dbufs; slot order per K-tile
// [A0,B0,B1,A1]; stage 1 half-tile/phase, 7 ahead; vmcnt(6) at K-tile starts.
// LDS swizzle: col ^= (row&7)<<3 on source + ds_read (rule 21).
// ---------------------------------------------------------------------------
template <int K, int N, bool GELU, bool BIAS, bool OUTBF>
__global__ __launch_bounds__(512, 2) void gemm8p_kernel(
    const unsigned short* __restrict__ Amat,
    const unsigned short* __restrict__ Bmat,
    const float* __restrict__ bias,
    const int* __restrict__ tiles,
    const int* __restrict__ perm,
    unsigned short* __restrict__ out_bf,
    float* __restrict__ out_f) {
  extern __shared__ unsigned short lds[];  // A: [2][2][8192], B at +32768
  constexpr int NKt = K / 64;

  // XCD-chunked block swizzle (grid % 8 == 0)
  const int total = MAXT * (N / 256);
  const int cpx = total >> 3;
  const int bid = blockIdx.x;
  const int id = (bid & 7) * cpx + (bid >> 3);
  const int ti = id % MAXT;
  const int n0 = (id / MAXT) * 256;

  const int e  = tiles[ti * 4 + 0];
  const int rs = tiles[ti * 4 + 1];
  const int nr = tiles[ti * 4 + 2];
  if (nr == 0) return;

  const int t = threadIdx.x;
  const int l = t & 63;
  const int w = t >> 6;
  const int r0 = (w >> 2) * 64;   // 0 / 64
  const int c0 = (w & 3) * 32;    // 0 / 32 / 64 / 96

  const unsigned short* Bp = Bmat + (size_t)e * N * K;

  auto ldsA = [&](int buf, int ha) { return lds + (buf * 2 + ha) * 8192; };
  auto ldsB = [&](int buf, int hb) { return lds + 32768 + (buf * 2 + hb) * 8192; };

  // Stage one half-tile (16KB): 2 issues x 512 thr x 16B. Linear LDS dest,
  // inverse-swizzled global source.
  auto stage = [&](int H) {
    const int slot = H & 3;        // 0:A rows0-127  1:B cols0-127  2:B cols128-255  3:A rows128-255
    const int ktS = H >> 2, buf = ktS & 1, k0 = ktS * 64;
#pragma unroll
    for (int i = 0; i < 2; ++i) {
      int elem = (i * 512 + t) * 8;
      int r = elem >> 6, cp = elem & 63;
      int cl = cp ^ ((r & 7) << 3);
      const unsigned short* src;
      unsigned short* dst;
      if (slot == 0 || slot == 3) {
        src = Amat + (size_t)(rs + (slot == 3 ? 128 : 0) + r) * K + k0 + cl;
        dst = ldsA(buf, slot == 3 ? 1 : 0) + elem;
      } else {
        src = Bp + (size_t)(n0 + (slot == 2 ? 128 : 0) + r) * K + k0 + cl;
        dst = ldsB(buf, slot == 2 ? 1 : 0) + elem;
      }
      __builtin_amdgcn_global_load_lds(
          (const __attribute__((address_space(1))) unsigned int*)src,
          (__attribute__((address_space(3))) unsigned int*)dst, 16, 0, 0);
    }
  };

  short8 aF[4][2], bF0[2][2], bF1[2][2];
  f32x4 acc[2][2][4][2] = {};

  auto loadA = [&](int buf, int ha) {
#pragma unroll
    for (int mr = 0; mr < 4; ++mr)
#pragma unroll
      for (int ks = 0; ks < 2; ++ks) {
        int r = r0 + mr * 16 + (l & 15);
        int c = (ks * 32 + (l >> 4) * 8) ^ ((r & 7) << 3);
        aF[mr][ks] = *(const short8*)(ldsA(buf, ha) + r * 64 + c);
      }
  };
  auto loadB = [&](int buf, int hb, short8 (*bF)[2]) {
#pragma unroll
    for (int nc = 0; nc < 2; ++nc)
#pragma unroll
      for (int ks = 0; ks < 2; ++ks) {
        int r = c0 + nc * 16 + (l & 15);
        int c = (ks * 32 + (l >> 4) * 8) ^ ((r & 7) << 3);
        bF[nc][ks] = *(const short8*)(ldsB(buf, hb) + r * 64 + c);
      }
  };
  auto mfmaQ = [&](int qr, int qc, short8 (*bF)[2]) {
    __builtin_amdgcn_s_setprio(1);
#pragma unroll
    for (int mr = 0; mr < 4; ++mr)
#pragma unroll
      for (int nc = 0; nc < 2; ++nc)
#pragma unroll
        for (int ks = 0; ks < 2; ++ks)
          acc[qr][qc][mr][nc] = __builtin_amdgcn_mfma_f32_16x16x32_bf16(
              aF[mr][ks], bF[nc][ks], acc[qr][qc][mr][nc], 0, 0, 0);
    __builtin_amdgcn_s_setprio(0);
  };

  // Prologue: stage K-tile 0 fully + first 3 halves of K-tile 1.
#pragma unroll
  for (int H = 0; H < 4; ++H) stage(H);
  asm volatile("s_waitcnt vmcnt(4)" ::: "memory");
#pragma unroll
  for (int H = 4; H < 7; ++H) stage(H);

  for (int kt = 0; kt < NKt - 1; ++kt) {
    const int buf = kt & 1;
    // phase 0: reads A0+B0 (12 b128), stage slot A0(kt+2... H=4kt+7 -> A1 of kt+1)
    asm volatile("s_waitcnt vmcnt(6)" ::: "memory");
    __builtin_amdgcn_s_barrier();
    loadA(buf, 0);
    loadB(buf, 0, bF0);
    { int H = 4 * kt + 7;  if (H < 4 * NKt) stage(H); }
    __builtin_amdgcn_s_barrier();
    mfmaQ(0, 0, bF0);
    // phase 1: reads B1 (4 b128)
    __builtin_amdgcn_s_barrier();
    loadB(buf, 1, bF1);
    { int H = 4 * kt + 8;  if (H < 4 * NKt) stage(H); }
    __builtin_amdgcn_s_barrier();
    mfmaQ(0, 1, bF1);
    // phase 2: reads A1 (8 b128)
    __builtin_amdgcn_s_barrier();
    loadA(buf, 1);
    { int H = 4 * kt + 9;  if (H < 4 * NKt) stage(H); }
    __builtin_amdgcn_s_barrier();
    mfmaQ(1, 0, bF0);
    // phase 3: no reads
    __builtin_amdgcn_s_barrier();
    { int H = 4 * kt + 10; if (H < 4 * NKt) stage(H); }
    __builtin_amdgcn_s_barrier();
    mfmaQ(1, 1, bF1);
  }
  // Last K-tile: full drain once, then 4 compute phases, no staging.
  {
    const int buf = (NKt - 1) & 1;
    asm volatile("s_waitcnt vmcnt(0)" ::: "memory");
    __builtin_amdgcn_s_barrier();
    loadA(buf, 0);
    loadB(buf, 0, bF0);
    __builtin_amdgcn_s_barrier();
    mfmaQ(0, 0, bF0);
    __builtin_amdgcn_s_barrier();
    loadB(buf, 1, bF1);
    __builtin_amdgcn_s_barrier();
    mfmaQ(0, 1, bF1);
    __builtin_amdgcn_s_barrier();
    loadA(buf, 1);
    __builtin_amdgcn_s_barrier();
    mfmaQ(1, 0, bF0);
    __builtin_amdgcn_s_barrier();
    mfmaQ(1, 1, bF1);
  }

  // Epilogue.  D frag: A-side = (l>>4)*4 + reg, B-side = l&15.
  const int lr4 = (l >> 4) * 4;
  const int lc  = l & 15;
#pragma unroll
  for (int qr = 0; qr < 2; ++qr)
#pragma unroll
    for (int mr = 0; mr < 4; ++mr)
#pragma unroll
      for (int rg = 0; rg < 4; ++rg) {
        int row = qr * 128 + r0 + mr * 16 + lr4 + rg;
        if (row < nr) {
          if constexpr (OUTBF) {
            unsigned short* dst = out_bf + (size_t)(rs + row) * N + n0;
#pragma unroll
            for (int qc = 0; qc < 2; ++qc)
#pragma unroll
              for (int nc = 0; nc < 2; ++nc) {
                float v = acc[qr][qc][mr][nc][rg];
                if constexpr (GELU) v = gelu_exact(v);
                dst[qc * 128 + c0 + nc * 16 + lc] = f2bf(v);
              }
          } else {
            int orig = perm[rs + row];
            float* dst = out_f + (size_t)orig * N + n0;
#pragma unroll
            for (int qc = 0; qc < 2; ++qc)
#pragma unroll
              for (int nc = 0; nc < 2; ++nc) {
                float v = acc[qr][qc][mr][nc][rg];
                if constexpr (BIAS)
                  v += bias[(size_t)e * N + n0 + qc * 128 + c0 + nc * 16 + lc];
                dst[qc * 128 + c0 + nc * 16 + lc] = v;
              }
          }
        }
      }
}

// ---------------------------------------------------------------------------
extern "C" void kernel_launch(void* const* d_in, const int* in_sizes, int n_in,
                              void* d_out, int out_size, void* d_ws, size_t ws_size,
                              hipStream_t stream) {
  const float* x  = (const float*)d_in[0];
  const int*  eid = (const int*)d_in[1];
  const float* W1 = (const float*)d_in[2];
  const float* W2 = (const float*)d_in[3];
  const float* b2 = (const float*)d_in[4];
  float* y = (float*)d_out;

  char* ws = (char*)d_ws;
  int* perm  = (int*)ws;                                   // 32KB
  int* tiles = (int*)(ws + 32768);
  unsigned short* xg = (unsigned short*)(ws + 36864);      // [kB+256][kD]
  size_t xg_bytes = (size_t)(kB + BM) * kD * 2;            // 17,301,504
  unsigned short* h  = (unsigned short*)(ws + 36864 + xg_bytes);  // [kB+256][kH1]
  size_t h_bytes = (size_t)(kB + BM) * kH1 * 2;            // 69,206,016
  unsigned short* Wb = (unsigned short*)(ws + 36864 + xg_bytes + h_bytes);  // 64MB

  constexpr int kWelems8 = kE * kH1 * kD / 8;

  auto g1 = gemm8p_kernel<kD, kH1, true, false, true>;
  auto g2 = gemm8p_kernel<kH1, kO, false, true, false>;
  hipFuncSetAttribute((const void*)g1, hipFuncAttributeMaxDynamicSharedMemorySize, 131072);
  hipFuncSetAttribute((const void*)g2, hipFuncAttributeMaxDynamicSharedMemorySize, 131072);

  setup_kernel<<<1, 256, 0, stream>>>(eid, perm, tiles);
  gather_kernel<<<(kB * kD / 8) / 256, 256, 0, stream>>>(x, perm, xg);

  convert_kernel<<<2048, 256, 0, stream>>>(W1, Wb, kWelems8);
  g1<<<MAXT * (kH1 / 256), 512, 131072, stream>>>(xg, Wb, nullptr, tiles, perm, h, nullptr);

  convert_kernel<<<2048, 256, 0, stream>>>(W2, Wb, kWelems8);
  g2<<<MAXT * (kO / 256), 512, 131072, stream>>>(h, Wb, b2, tiles, perm, nullptr, y);
}

// Round 5
// 321.051 us; speedup vs baseline: 1.3871x; 1.0379x over previous
//
#include <hip/hip_runtime.h>
#include <hip/hip_bf16.h>
#include <math.h>

// Problem constants
constexpr int kD  = 1024;
constexpr int kH1 = 4096;
constexpr int kO  = 1024;
constexpr int kE  = 8;
constexpr int kB  = 8192;

constexpr int BM = 256;            // row-tile
constexpr int MAXT = kB / BM + kE; // 40 row-tiles upper bound

typedef __attribute__((ext_vector_type(8))) short short8;
typedef __attribute__((ext_vector_type(4))) float f32x4;

__device__ __forceinline__ unsigned short f2bf(float f) {
  unsigned int u = __float_as_uint(f);
  u += 0x7fffu + ((u >> 16) & 1u);
  return (unsigned short)(u >> 16);
}

// tanh-form gelu: max |err| vs exact erf-gelu ~1e-3 (negligible vs bf16
// rounding already present).  ~9 VALU ops incl 2 transcendental vs erff ~25+.
__device__ __forceinline__ float gelu_fast(float x) {
  float u = 0.7978845608028654f * (x + 0.044715f * x * x * x);
  float eu = __expf(2.0f * u);          // inf for large u -> th=1; 0 -> th=-1
  float th = 1.0f - 2.0f / (eu + 1.0f);
  return 0.5f * x * (1.0f + th);
}

// ---------------------------------------------------------------------------
// Setup: counts per expert, permutation (grouped by expert), 256-row tiles.
// ---------------------------------------------------------------------------
__global__ __launch_bounds__(256) void setup_kernel(const int* __restrict__ eid,
                                                    int* __restrict__ perm,
                                                    int* __restrict__ tiles) {
  __shared__ int cnt[kE];
  __shared__ int off[kE];
  __shared__ int cur[kE];
  int t = threadIdx.x;
  if (t < kE) { cnt[t] = 0; cur[t] = 0; }
  __syncthreads();
  for (int i = t; i < kB; i += 256) atomicAdd(&cnt[eid[i]], 1);
  __syncthreads();
  if (t == 0) {
    int o = 0, nt = 0;
    for (int e = 0; e < kE; ++e) {
      off[e] = o;
      int c = cnt[e];
      for (int r = 0; r < c; r += BM) {
        tiles[nt * 4 + 0] = e;
        tiles[nt * 4 + 1] = o + r;
        tiles[nt * 4 + 2] = (c - r < BM) ? (c - r) : BM;
        tiles[nt * 4 + 3] = 0;
        ++nt;
      }
      o += c;
    }
    for (; nt < MAXT; ++nt) {
      tiles[nt * 4 + 0] = 0; tiles[nt * 4 + 1] = 0;
      tiles[nt * 4 + 2] = 0; tiles[nt * 4 + 3] = 0;
    }
  }
  __syncthreads();
  for (int i = t; i < kB; i += 256) {
    int e = eid[i];
    int p = off[e] + atomicAdd(&cur[e], 1);
    perm[p] = i;
  }
}

// ---------------------------------------------------------------------------
// Gather x rows into perm order, fp32 -> bf16.  xg is [kB+BM][kD] bf16.
// ---------------------------------------------------------------------------
__global__ __launch_bounds__(256) void gather_kernel(const float* __restrict__ x,
                                                     const int* __restrict__ perm,
                                                     unsigned short* __restrict__ xg) {
  int idx = blockIdx.x * 256 + threadIdx.x;
  int pos = idx >> 7;
  int c   = (idx & 127) << 3;
  int row = perm[pos];
  const float4* s = (const float4*)(x + (size_t)row * kD + c);
  float4 f0 = s[0], f1 = s[1];
  short8 v;
  v[0] = (short)f2bf(f0.x); v[1] = (short)f2bf(f0.y);
  v[2] = (short)f2bf(f0.z); v[3] = (short)f2bf(f0.w);
  v[4] = (short)f2bf(f1.x); v[5] = (short)f2bf(f1.y);
  v[6] = (short)f2bf(f1.z); v[7] = (short)f2bf(f1.w);
  *(short8*)(xg + (size_t)pos * kD + c) = v;
}

// ---------------------------------------------------------------------------
// Bulk fp32 -> bf16 convert (weights).
// ---------------------------------------------------------------------------
__global__ __launch_bounds__(256) void convert_kernel(const float* __restrict__ src,
                                                      unsigned short* __restrict__ dst,
                                                      int n8) {
  int stride = gridDim.x * 256;
  for (int i = blockIdx.x * 256 + threadIdx.x; i < n8; i += stride) {
    const float4* s = (const float4*)(src + (size_t)i * 8);
    float4 f0 = s[0], f1 = s[1];
    short8 v;
    v[0] = (short)f2bf(f0.x); v[1] = (short)f2bf(f0.y);
    v[2] = (short)f2bf(f0.z); v[3] = (short)f2bf(f0.w);
    v[4] = (short)f2bf(f1.x); v[5] = (short)f2bf(f1.y);
    v[6] = (short)f2bf(f1.z); v[7] = (short)f2bf(f1.w);
    *(short8*)(dst + (size_t)i * 8) = v;
  }
}

// ---------------------------------------------------------------------------
// 256x256 8-phase grouped GEMM (m201-style).  C = A(bf16, K-major) x B^T.
// 512 threads = 8 waves; BK=64; 2 LDS dbufs; slot order [A0,B0,B1,A1];
// stage 1 half-tile/phase, 7 ahead; vmcnt(6) at K-tile starts.
// LDS swizzle: col ^= (row&7)<<3 on source + ds_read (rule 21).
// Block swizzle: 4ti x 4n0 chunks per XCD for L2 A+B panel sharing.
// ---------------------------------------------------------------------------
template <int K, int N, bool GELU, bool BIAS, bool OUTBF>
__global__ __launch_bounds__(512, 2) void gemm8p_kernel(
    const unsigned short* __restrict__ Amat,
    const unsigned short* __restrict__ Bmat,
    const float* __restrict__ bias,
    const int* __restrict__ tiles,
    const int* __restrict__ perm,
    unsigned short* __restrict__ out_bf,
    float* __restrict__ out_f) {
  extern __shared__ unsigned short lds[];  // A: [2][2][8192], B at +32768
  constexpr int NKt = K / 64;
  constexpr int Npan = N / 256;

  // XCD-chunked block swizzle: id walks 16-block chunks covering 4ti x 4n0.
  constexpr int total = MAXT * Npan;
  constexpr int cpx = total >> 3;
  constexpr int nchunks_n = (Npan >= 4) ? (Npan / 4) : 1;
  const int bid = blockIdx.x;
  const int id = (bid & 7) * cpx + (bid >> 3);
  const int chunk = id >> 4;
  const int a16 = id & 15;
  const int ti = (chunk / nchunks_n) * 4 + (a16 & 3);
  const int n0 = ((chunk % nchunks_n) * 4 + (a16 >> 2)) * 256;

  const int e  = tiles[ti * 4 + 0];
  const int rs = tiles[ti * 4 + 1];
  const int nr = tiles[ti * 4 + 2];
  if (nr == 0) return;

  const int t = threadIdx.x;
  const int l = t & 63;
  const int w = t >> 6;
  const int r0 = (w >> 2) * 64;   // 0 / 64
  const int c0 = (w & 3) * 32;    // 0 / 32 / 64 / 96

  const unsigned short* Bp = Bmat + (size_t)e * N * K;

  auto ldsA = [&](int buf, int ha) { return lds + (buf * 2 + ha) * 8192; };
  auto ldsB = [&](int buf, int hb) { return lds + 32768 + (buf * 2 + hb) * 8192; };

  // Precomputed per-lane swizzled LDS element offsets (loop-invariant).
  int offA[4][2], offB[2][2];
#pragma unroll
  for (int mr = 0; mr < 4; ++mr)
#pragma unroll
    for (int ks = 0; ks < 2; ++ks) {
      int r = r0 + mr * 16 + (l & 15);
      offA[mr][ks] = r * 64 + ((ks * 32 + (l >> 4) * 8) ^ ((r & 7) << 3));
    }
#pragma unroll
  for (int nc = 0; nc < 2; ++nc)
#pragma unroll
    for (int ks = 0; ks < 2; ++ks) {
      int r = c0 + nc * 16 + (l & 15);
      offB[nc][ks] = r * 64 + ((ks * 32 + (l >> 4) * 8) ^ ((r & 7) << 3));
    }

  // Stage one half-tile (16KB): 2 issues x 512 thr x 16B. Linear LDS dest,
  // inverse-swizzled global source.
  auto stage = [&](int H) {
    const int slot = H & 3;   // 0:A rows0-127  1:B cols0-127  2:B cols128-255  3:A rows128-255
    const int ktS = H >> 2, buf = ktS & 1, k0 = ktS * 64;
#pragma unroll
    for (int i = 0; i < 2; ++i) {
      int elem = (i * 512 + t) * 8;
      int r = elem >> 6, cp = elem & 63;
      int cl = cp ^ ((r & 7) << 3);
      const unsigned short* src;
      unsigned short* dst;
      if (slot == 0 || slot == 3) {
        src = Amat + (size_t)(rs + (slot == 3 ? 128 : 0) + r) * K + k0 + cl;
        dst = ldsA(buf, slot == 3 ? 1 : 0) + elem;
      } else {
        src = Bp + (size_t)(n0 + (slot == 2 ? 128 : 0) + r) * K + k0 + cl;
        dst = ldsB(buf, slot == 2 ? 1 : 0) + elem;
      }
      __builtin_amdgcn_global_load_lds(
          (const __attribute__((address_space(1))) unsigned int*)src,
          (__attribute__((address_space(3))) unsigned int*)dst, 16, 0, 0);
    }
  };

  short8 aF[4][2], bF0[2][2], bF1[2][2];
  f32x4 acc[2][2][4][2] = {};

  auto loadA = [&](int buf, int ha) {
    const unsigned short* base = ldsA(buf, ha);
#pragma unroll
    for (int mr = 0; mr < 4; ++mr)
#pragma unroll
      for (int ks = 0; ks < 2; ++ks)
        aF[mr][ks] = *(const short8*)(base + offA[mr][ks]);
  };
  auto loadB = [&](int buf, int hb, short8 (*bF)[2]) {
    const unsigned short* base = ldsB(buf, hb);
#pragma unroll
    for (int nc = 0; nc < 2; ++nc)
#pragma unroll
      for (int ks = 0; ks < 2; ++ks)
        bF[nc][ks] = *(const short8*)(base + offB[nc][ks]);
  };
  auto mfmaQ = [&](int qr, int qc, short8 (*bF)[2]) {
    __builtin_amdgcn_s_setprio(1);
#pragma unroll
    for (int mr = 0; mr < 4; ++mr)
#pragma unroll
      for (int nc = 0; nc < 2; ++nc)
#pragma unroll
        for (int ks = 0; ks < 2; ++ks)
          acc[qr][qc][mr][nc] = __builtin_amdgcn_mfma_f32_16x16x32_bf16(
              aF[mr][ks], bF[nc][ks], acc[qr][qc][mr][nc], 0, 0, 0);
    __builtin_amdgcn_s_setprio(0);
  };

  // Prologue: stage K-tile 0 fully + first 3 halves of K-tile 1.
#pragma unroll
  for (int H = 0; H < 4; ++H) stage(H);
  asm volatile("s_waitcnt vmcnt(4)" ::: "memory");
#pragma unroll
  for (int H = 4; H < 7; ++H) stage(H);

  for (int kt = 0; kt < NKt - 1; ++kt) {
    const int buf = kt & 1;
    // phase 0: reads A0+B0 (12 b128), stage
    asm volatile("s_waitcnt vmcnt(6)" ::: "memory");
    __builtin_amdgcn_s_barrier();
    loadA(buf, 0);
    loadB(buf, 0, bF0);
    { int H = 4 * kt + 7;  if (H < 4 * NKt) stage(H); }
    __builtin_amdgcn_s_barrier();
    mfmaQ(0, 0, bF0);
    // phase 1: reads B1 (4 b128)
    __builtin_amdgcn_s_barrier();
    loadB(buf, 1, bF1);
    { int H = 4 * kt + 8;  if (H < 4 * NKt) stage(H); }
    __builtin_amdgcn_s_barrier();
    mfmaQ(0, 1, bF1);
    // phase 2: reads A1 (8 b128)
    __builtin_amdgcn_s_barrier();
    loadA(buf, 1);
    { int H = 4 * kt + 9;  if (H < 4 * NKt) stage(H); }
    __builtin_amdgcn_s_barrier();
    mfmaQ(1, 0, bF0);
    // phase 3: no reads
    __builtin_amdgcn_s_barrier();
    { int H = 4 * kt + 10; if (H < 4 * NKt) stage(H); }
    __builtin_amdgcn_s_barrier();
    mfmaQ(1, 1, bF1);
  }
  // Last K-tile: full drain once, then 4 compute phases, no staging.
  {
    const int buf = (NKt - 1) & 1;
    asm volatile("s_waitcnt vmcnt(0)" ::: "memory");
    __builtin_amdgcn_s_barrier();
    loadA(buf, 0);
    loadB(buf, 0, bF0);
    __builtin_amdgcn_s_barrier();
    mfmaQ(0, 0, bF0);
    __builtin_amdgcn_s_barrier();
    loadB(buf, 1, bF1);
    __builtin_amdgcn_s_barrier();
    mfmaQ(0, 1, bF1);
    __builtin_amdgcn_s_barrier();
    loadA(buf, 1);
    __builtin_amdgcn_s_barrier();
    mfmaQ(1, 0, bF0);
    __builtin_amdgcn_s_barrier();
    mfmaQ(1, 1, bF1);
  }

  // Epilogue.  D frag: A-side = (l>>4)*4 + reg, B-side = l&15.
  const int lr4 = (l >> 4) * 4;
  const int lc  = l & 15;
#pragma unroll
  for (int qr = 0; qr < 2; ++qr)
#pragma unroll
    for (int mr = 0; mr < 4; ++mr)
#pragma unroll
      for (int rg = 0; rg < 4; ++rg) {
        int row = qr * 128 + r0 + mr * 16 + lr4 + rg;
        if (row < nr) {
          if constexpr (OUTBF) {
            unsigned short* dst = out_bf + (size_t)(rs + row) * N + n0;
#pragma unroll
            for (int qc = 0; qc < 2; ++qc)
#pragma unroll
              for (int nc = 0; nc < 2; ++nc) {
                float v = acc[qr][qc][mr][nc][rg];
                if constexpr (GELU) v = gelu_fast(v);
                dst[qc * 128 + c0 + nc * 16 + lc] = f2bf(v);
              }
          } else {
            int orig = perm[rs + row];
            float* dst = out_f + (size_t)orig * N + n0;
#pragma unroll
            for (int qc = 0; qc < 2; ++qc)
#pragma unroll
              for (int nc = 0; nc < 2; ++nc) {
                float v = acc[qr][qc][mr][nc][rg];
                if constexpr (BIAS)
                  v += bias[(size_t)e * N + n0 + qc * 128 + c0 + nc * 16 + lc];
                dst[qc * 128 + c0 + nc * 16 + lc] = v;
              }
          }
        }
      }
}

// ---------------------------------------------------------------------------
extern "C" void kernel_launch(void* const* d_in, const int* in_sizes, int n_in,
                              void* d_out, int out_size, void* d_ws, size_t ws_size,
                              hipStream_t stream) {
  const float* x  = (const float*)d_in[0];
  const int*  eid = (const int*)d_in[1];
  const float* W1 = (const float*)d_in[2];
  const float* W2 = (const float*)d_in[3];
  const float* b2 = (const float*)d_in[4];
  float* y = (float*)d_out;

  char* ws = (char*)d_ws;
  int* perm  = (int*)ws;                                   // 32KB
  int* tiles = (int*)(ws + 32768);
  unsigned short* xg = (unsigned short*)(ws + 36864);      // [kB+256][kD]
  size_t xg_bytes = (size_t)(kB + BM) * kD * 2;            // 17,301,504
  unsigned short* h  = (unsigned short*)(ws + 36864 + xg_bytes);  // [kB+256][kH1]
  size_t h_bytes = (size_t)(kB + BM) * kH1 * 2;            // 69,206,016
  unsigned short* Wb = (unsigned short*)(ws + 36864 + xg_bytes + h_bytes);  // 64MB

  constexpr int kWelems8 = kE * kH1 * kD / 8;

  auto g1 = gemm8p_kernel<kD, kH1, true, false, true>;
  auto g2 = gemm8p_kernel<kH1, kO, false, true, false>;
  hipFuncSetAttribute((const void*)g1, hipFuncAttributeMaxDynamicSharedMemorySize, 131072);
  hipFuncSetAttribute((const void*)g2, hipFuncAttributeMaxDynamicSharedMemorySize, 131072);

  setup_kernel<<<1, 256, 0, stream>>>(eid, perm, tiles);
  gather_kernel<<<(kB * kD / 8) / 256, 256, 0, stream>>>(x, perm, xg);

  convert_kernel<<<2048, 256, 0, stream>>>(W1, Wb, kWelems8);
  g1<<<MAXT * (kH1 / 256), 512, 131072, stream>>>(xg, Wb, nullptr, tiles, perm, h, nullptr);

  convert_kernel<<<2048, 256, 0, stream>>>(W2, Wb, kWelems8);
  g2<<<MAXT * (kO / 256), 512, 131072, stream>>>(h, Wb, b2, tiles, perm, nullptr, y);
}